// Round 2
// baseline (140.154 us; speedup 1.0000x reference)
//
#include <hip/hip_runtime.h>

// Problem constants
#define N_TOTAL 32768
#define D_DIM   512
#define C_DIM   64
#define K_DIM   16
#define M_DIM   128
#define NODES_  15
#define ROWS    16   // rows per block in main kernel

// L(M, C*K) -> Lt(C*K, M), fp32. 131072 elements (512 KB).
__global__ __launch_bounds__(256) void transpose_L_kernel(
    const float* __restrict__ L, float* __restrict__ Lt)
{
    int idx = blockIdx.x * 256 + threadIdx.x;      // 512 blocks * 256
    float v = L[idx];                               // coalesced read
    int m  = idx >> 10;                             // 0..127
    int ck = idx & 1023;                            // 0..1023
    Lt[ck * M_DIM + m] = v;                         // scattered write (tiny, once)
}

__global__ __launch_bounds__(256) void halut_kernel(
    const float* __restrict__ I,
    const float* __restrict__ T,
    const int* __restrict__ dims,
    const float* __restrict__ Lt,
    float* __restrict__ out)
{
    __shared__ __align__(16) float sI[ROWS * D_DIM]; // 32 KB
    __shared__ float sT[C_DIM * NODES_];             // 3.75 KB
    __shared__ int   sDims[C_DIM * 4];               // 1 KB
    __shared__ int   sCode[ROWS * 65];               // padded stride 65

    const int tid = threadIdx.x;
    const int n0  = blockIdx.x * ROWS;

    // ---- stage dims, T ----
    sDims[tid] = dims[tid];                          // 256 threads, 256 dims
    for (int j = tid; j < C_DIM * NODES_; j += 256)
        sT[j] = T[j];

    // ---- stage 16 rows of I: 16*512*4 B = 32 KB contiguous ----
    {
        const float4* src = (const float4*)(I + (size_t)n0 * D_DIM);
        float4* dst = (float4*)sI;
        #pragma unroll
        for (int p = 0; p < 8; ++p)
            dst[p * 256 + tid] = src[p * 256 + tid];
    }
    __syncthreads();

    // ---- codes: ROWS*C = 1024 depth-4 tree descents, 4 per thread ----
    // Forward of the STE reference: sign(h) drives a binary descent; the
    // argmax leaf is exactly the descent leaf (any other leaf scores <= 2 < 4).
    // h==0 -> sign 0 -> tie between subtree maxima; argmax picks smaller k -> bit 0.
    for (int t = tid; t < ROWS * C_DIM; t += 256) {
        int row = t >> 6;
        int c   = t & 63;
        const float* v = sI + row * D_DIM;
        int node = 0, k = 0;
        #pragma unroll
        for (int l = 0; l < 4; ++l) {
            float h = v[sDims[(c << 2) + l]] - sT[c * NODES_ + node];
            int bit = (h > 0.0f) ? 1 : 0;
            k = (k << 1) | bit;
            node = (node << 1) + 1 + bit;
        }
        sCode[row * 65 + c] = k;
    }
    __syncthreads();

    // ---- accumulate: thread owns (row r, columns m = q*8 .. q*8+7) ----
    const int r = tid >> 4;      // 0..15
    const int q = tid & 15;      // 0..15
    const int* codeRow = sCode + r * 65;

    float4 acc0 = make_float4(0.f, 0.f, 0.f, 0.f);
    float4 acc1 = make_float4(0.f, 0.f, 0.f, 0.f);

    #pragma unroll 4
    for (int c = 0; c < C_DIM; ++c) {
        int k = codeRow[c];                          // LDS broadcast in 16-lane group
        const float4* lrow = (const float4*)(Lt + (((c << 4) + k) << 7) + (q << 3));
        float4 a = lrow[0];
        float4 b = lrow[1];
        acc0.x += a.x; acc0.y += a.y; acc0.z += a.z; acc0.w += a.w;
        acc1.x += b.x; acc1.y += b.y; acc1.z += b.z; acc1.w += b.w;
    }

    float4* o = (float4*)(out + (size_t)(n0 + r) * M_DIM + (q << 3));
    o[0] = acc0;
    o[1] = acc1;
}

extern "C" void kernel_launch(void* const* d_in, const int* in_sizes, int n_in,
                              void* d_out, int out_size, void* d_ws, size_t ws_size,
                              hipStream_t stream) {
    // setup_inputs order: I(0) T(1) L(2) S(3) B(4) dims(5) temp(6) — all fp32, dims int32
    const float* I    = (const float*)d_in[0];
    const float* T    = (const float*)d_in[1];
    const float* L    = (const float*)d_in[2];
    const int*   dims = (const int*)d_in[5];
    // S, B, temp unused: forward value = tree descent + LUT sum (see analysis)

    float* Lt = (float*)d_ws;                        // 512 KB scratch

    hipLaunchKernelGGL(transpose_L_kernel, dim3((C_DIM * K_DIM * M_DIM) / 256), dim3(256), 0, stream,
                       L, Lt);
    hipLaunchKernelGGL(halut_kernel, dim3(N_TOTAL / ROWS), dim3(256), 0, stream,
                       I, T, dims, Lt, (float*)d_out);
}

// Round 3
// 130.057 us; speedup vs baseline: 1.0776x; 1.0776x over previous
//
#include <hip/hip_runtime.h>

#define N_TOTAL 32768
#define D_DIM   512
#define C_DIM   64
#define K_DIM   16
#define M_DIM   128
#define NODES_  15
#define ROWS    16

typedef unsigned short u16;
typedef unsigned int   u32;

__device__ __forceinline__ u32 f2bf_bits(float f) {
    u32 u = __float_as_uint(f);
    return (u + 0x7FFFu + ((u >> 16) & 1u)) >> 16;   // RNE
}
__device__ __forceinline__ float bf_lo(u32 u) { return __uint_as_float(u << 16); }
__device__ __forceinline__ float bf_hi(u32 u) { return __uint_as_float(u & 0xFFFF0000u); }

// ---------------------------------------------------------------------------
// Kernel T: pair-merged LUT. LUT2[p][kk][m] (bf16), p=0..31, kk=k0|(k1<<4):
//   LUT2 = L[m][(2p)*16+k0] + L[m][(2p+1)*16+k1]
// 32*256*128 bf16 = 2 MB, L2-resident. L itself is 512 KB (L2-resident).
// ---------------------------------------------------------------------------
__global__ __launch_bounds__(256) void build_lut_kernel(
    const float* __restrict__ L, u16* __restrict__ LUT)
{
    int idx = blockIdx.x * 256 + threadIdx.x;   // 131072 threads
    int q  = idx & 15;                          // col-group (8 cols)
    int kk = (idx >> 4) & 255;
    int p  = idx >> 12;                         // 0..31
    int c0 = (2 * p) * 16 + (kk & 15);          // offset within an L row
    int c1 = (2 * p + 1) * 16 + (kk >> 4);
    u32 w[4];
    #pragma unroll
    for (int h = 0; h < 4; ++h) {
        int m0 = q * 8 + 2 * h;
        float a0 = L[m0 * 1024 + c0]       + L[m0 * 1024 + c1];
        float a1 = L[(m0 + 1) * 1024 + c0] + L[(m0 + 1) * 1024 + c1];
        w[h] = f2bf_bits(a0) | (f2bf_bits(a1) << 16);
    }
    *(uint4*)(LUT + (size_t)((p << 8) | kk) * M_DIM + q * 8) =
        make_uint4(w[0], w[1], w[2], w[3]);
}

// ---------------------------------------------------------------------------
// Kernel A: depth-4 tree descent per (row, class); 4-bit codes packed 8/word.
// codes[row*8 + w] holds classes 8w..8w+7 (nibble j = class 8w+j), so byte b
// of word w = kk for pair p = 4w+b. HBM-bound on I (64 MB).
// ---------------------------------------------------------------------------
__global__ __launch_bounds__(256) void codes_kernel(
    const float* __restrict__ I,
    const float* __restrict__ T,
    const int* __restrict__ dims,
    u32* __restrict__ codes)
{
    __shared__ __align__(16) float sI[ROWS * D_DIM]; // 32 KB
    __shared__ float sT[C_DIM * NODES_];
    __shared__ int   sDims[C_DIM * 4];
    __shared__ int   sCode[ROWS * 65];               // pad stride 65

    const int tid = threadIdx.x;
    const int n0  = blockIdx.x * ROWS;

    sDims[tid] = dims[tid];
    for (int j = tid; j < C_DIM * NODES_; j += 256) sT[j] = T[j];

    {   // stage 16 rows: 32 KB contiguous
        const float4* src = (const float4*)(I + (size_t)n0 * D_DIM);
        float4* dst = (float4*)sI;
        #pragma unroll
        for (int p = 0; p < 8; ++p)
            dst[p * 256 + tid] = src[p * 256 + tid];
    }
    __syncthreads();

    // sign(h) drives a binary descent; argmax leaf == descent leaf.
    // h==0 -> bit 0 (matches first-argmax tie rule).
    for (int t = tid; t < ROWS * C_DIM; t += 256) {
        int row = t >> 6;
        int c   = t & 63;
        const float* v = sI + row * D_DIM;
        int node = 0, k = 0;
        #pragma unroll
        for (int l = 0; l < 4; ++l) {
            float h = v[sDims[(c << 2) + l]] - sT[c * NODES_ + node];
            int bit = (h > 0.0f) ? 1 : 0;
            k = (k << 1) | bit;
            node = (node << 1) + 1 + bit;
        }
        sCode[row * 65 + c] = k;
    }
    __syncthreads();

    if (tid < 128) {                                 // pack 4-bit codes
        int r = tid >> 3, w = tid & 7;
        const int* sc = sCode + r * 65 + w * 8;
        u32 word = 0;
        #pragma unroll
        for (int j = 0; j < 8; ++j) word |= ((u32)sc[j]) << (4 * j);
        codes[(size_t)(n0 + r) * 8 + w] = word;      // coalesced 512 B/block
    }
}

// ---------------------------------------------------------------------------
// Kernel B: out[n,m] = sum_p LUT2[p][kk(n,p)][m]. 32 iters x 16 B L2 load.
// Thread = (row r, col-group q): fully-coalesced float4x2 output stores.
// No big LDS -> high occupancy; 268 MB read from L2.
// ---------------------------------------------------------------------------
__global__ __launch_bounds__(256) void accum_kernel(
    const u32* __restrict__ codes,
    const u16* __restrict__ LUT,
    float* __restrict__ out)
{
    __shared__ u32 sC[ROWS * 8];
    const int tid = threadIdx.x;
    const int n0  = blockIdx.x * ROWS;

    if (tid < 128) sC[tid] = codes[(size_t)n0 * 8 + tid];
    __syncthreads();

    const int r = tid >> 4;      // 0..15
    const int q = tid & 15;      // 0..15

    u32 cw[8];
    #pragma unroll
    for (int w = 0; w < 8; ++w) cw[w] = sC[r * 8 + w];   // LDS broadcast

    float4 acc0 = make_float4(0.f, 0.f, 0.f, 0.f);
    float4 acc1 = make_float4(0.f, 0.f, 0.f, 0.f);

    #pragma unroll
    for (int p = 0; p < 32; ++p) {
        u32 kk = (cw[p >> 2] >> ((p & 3) * 8)) & 255u;
        const uint4 v = *(const uint4*)(LUT + (size_t)(((p << 8) | kk) << 7) + (q << 3));
        acc0.x += bf_lo(v.x); acc0.y += bf_hi(v.x);
        acc0.z += bf_lo(v.y); acc0.w += bf_hi(v.y);
        acc1.x += bf_lo(v.z); acc1.y += bf_hi(v.z);
        acc1.z += bf_lo(v.w); acc1.w += bf_hi(v.w);
    }

    float4* o = (float4*)(out + (size_t)(n0 + r) * M_DIM + (q << 3));
    o[0] = acc0;
    o[1] = acc1;
}

extern "C" void kernel_launch(void* const* d_in, const int* in_sizes, int n_in,
                              void* d_out, int out_size, void* d_ws, size_t ws_size,
                              hipStream_t stream) {
    // inputs: I(0) T(1) L(2) S(3) B(4) dims(5) temp(6) — fp32, dims int32
    const float* I    = (const float*)d_in[0];
    const float* T    = (const float*)d_in[1];
    const float* L    = (const float*)d_in[2];
    const int*   dims = (const int*)d_in[5];

    u32* codes = (u32*)d_ws;                               // 1 MB
    u16* LUT   = (u16*)((char*)d_ws + (1 << 20));          // 2 MB

    hipLaunchKernelGGL(build_lut_kernel, dim3(512), dim3(256), 0, stream, L, LUT);
    hipLaunchKernelGGL(codes_kernel, dim3(N_TOTAL / ROWS), dim3(256), 0, stream,
                       I, T, dims, codes);
    hipLaunchKernelGGL(accum_kernel, dim3(N_TOTAL / ROWS), dim3(256), 0, stream,
                       codes, LUT, (float*)d_out);
}

// Round 4
// 124.827 us; speedup vs baseline: 1.1228x; 1.0419x over previous
//
#include <hip/hip_runtime.h>

#define N_TOTAL 32768
#define D_DIM   512
#define C_DIM   64
#define K_DIM   16
#define M_DIM   128
#define NODES_  15
#define ROWS    16

typedef unsigned short u16;
typedef unsigned int   u32;

__device__ __forceinline__ u32 f2bf_bits(float f) {
    u32 u = __float_as_uint(f);
    return (u + 0x7FFFu + ((u >> 16) & 1u)) >> 16;   // RNE
}
__device__ __forceinline__ float bf_lo(u32 u) { return __uint_as_float(u << 16); }
__device__ __forceinline__ float bf_hi(u32 u) { return __uint_as_float(u & 0xFFFF0000u); }

// ---------------------------------------------------------------------------
// Kernel 1: pair-merged LUT. LUT2[p][kk][m] (bf16), p=0..31, kk=k0|(k1<<4):
//   LUT2 = L[m][(2p)*16+k0] + L[m][(2p+1)*16+k1]
// 32*256*128 bf16 = 2 MB (L2/L3-resident). L itself is 512 KB.
// ---------------------------------------------------------------------------
__global__ __launch_bounds__(256) void build_lut_kernel(
    const float* __restrict__ L, u16* __restrict__ LUT)
{
    int idx = blockIdx.x * 256 + threadIdx.x;   // 131072 threads
    int q  = idx & 15;                          // col-group (8 cols)
    int kk = (idx >> 4) & 255;
    int p  = idx >> 12;                         // 0..31
    int c0 = (2 * p) * 16 + (kk & 15);
    int c1 = (2 * p + 1) * 16 + (kk >> 4);
    u32 w[4];
    #pragma unroll
    for (int h = 0; h < 4; ++h) {
        int m0 = q * 8 + 2 * h;
        float a0 = L[m0 * 1024 + c0]       + L[m0 * 1024 + c1];
        float a1 = L[(m0 + 1) * 1024 + c0] + L[(m0 + 1) * 1024 + c1];
        w[h] = f2bf_bits(a0) | (f2bf_bits(a1) << 16);
    }
    *(uint4*)(LUT + (size_t)((p << 8) | kk) * M_DIM + q * 8) =
        make_uint4(w[0], w[1], w[2], w[3]);
}

// ---------------------------------------------------------------------------
// Kernel 2 (fused): per block of 16 rows —
//   phase 1: depth-4 tree descent per (row, class) with direct global gathers
//            on I (each wave's gathers stay within its row's 16 cache lines);
//   phase 2: out[n,m] = sum_p LUT2[p][kk(n,p)][m], 32 x 16-B L2 loads/thread.
// Small LDS (~9 KB) -> VGPR-limited occupancy; HBM (I) and L2 (LUT) phases
// overlap across resident blocks.
// Forward of the STE reference: sign(h) drives a binary descent; argmax leaf
// == descent leaf (any other leaf scores <= 2 < 4). h==0 -> bit 0 == argmax
// first-max tie rule.
// ---------------------------------------------------------------------------
__global__ __launch_bounds__(256) void fused_kernel(
    const float* __restrict__ I,
    const float* __restrict__ T,
    const int* __restrict__ dims,
    const u16* __restrict__ LUT,
    float* __restrict__ out)
{
    __shared__ float sT[C_DIM * NODES_];    // 3.75 KB
    __shared__ int   sDims[C_DIM * 4];      // 1 KB
    __shared__ int   sCode[ROWS * 65];      // 4.1 KB, pad stride 65

    const int tid = threadIdx.x;
    const int n0  = blockIdx.x * ROWS;

    sDims[tid] = dims[tid];
    for (int j = tid; j < C_DIM * NODES_; j += 256) sT[j] = T[j];
    __syncthreads();

    // ---- phase 1: codes. Wave w handles row (t>>6), lanes = 64 classes. ----
    for (int t = tid; t < ROWS * C_DIM; t += 256) {
        int row = t >> 6;
        int c   = t & 63;
        const float* v = I + (size_t)(n0 + row) * D_DIM;
        int node = 0, k = 0;
        #pragma unroll
        for (int l = 0; l < 4; ++l) {
            float h = v[sDims[(c << 2) + l]] - sT[c * NODES_ + node];
            int bit = (h > 0.0f) ? 1 : 0;
            k = (k << 1) | bit;
            node = (node << 1) + 1 + bit;
        }
        sCode[row * 65 + c] = k;
    }
    __syncthreads();

    // ---- phase 2: accumulate. Thread = (row r, cols q*8..q*8+7). ----
    const int r = tid >> 4;      // 0..15
    const int q = tid & 15;      // 0..15
    const int* codeRow = sCode + r * 65;

    float4 acc0 = make_float4(0.f, 0.f, 0.f, 0.f);
    float4 acc1 = make_float4(0.f, 0.f, 0.f, 0.f);

    #pragma unroll
    for (int p = 0; p < 32; ++p) {
        u32 kk = (u32)codeRow[2 * p] | ((u32)codeRow[2 * p + 1] << 4);  // LDS broadcast
        const uint4 v = *(const uint4*)(LUT + (size_t)(((p << 8) | kk) << 7) + (q << 3));
        acc0.x += bf_lo(v.x); acc0.y += bf_hi(v.x);
        acc0.z += bf_lo(v.y); acc0.w += bf_hi(v.y);
        acc1.x += bf_lo(v.z); acc1.y += bf_hi(v.z);
        acc1.z += bf_lo(v.w); acc1.w += bf_hi(v.w);
    }

    float4* o = (float4*)(out + (size_t)(n0 + r) * M_DIM + (q << 3));
    o[0] = acc0;
    o[1] = acc1;
}

extern "C" void kernel_launch(void* const* d_in, const int* in_sizes, int n_in,
                              void* d_out, int out_size, void* d_ws, size_t ws_size,
                              hipStream_t stream) {
    // inputs: I(0) T(1) L(2) S(3) B(4) dims(5) temp(6) — fp32, dims int32
    const float* I    = (const float*)d_in[0];
    const float* T    = (const float*)d_in[1];
    const float* L    = (const float*)d_in[2];
    const int*   dims = (const int*)d_in[5];

    u16* LUT = (u16*)d_ws;                                 // 2 MB scratch

    hipLaunchKernelGGL(build_lut_kernel, dim3(512), dim3(256), 0, stream, L, LUT);
    hipLaunchKernelGGL(fused_kernel, dim3(N_TOTAL / ROWS), dim3(256), 0, stream,
                       I, T, dims, LUT, (float*)d_out);
}